// Round 11
// baseline (72.317 us; speedup 1.0000x reference)
//
#include <hip/hip_runtime.h>
#include <hip/hip_bf16.h>

// SelfAttention: B=4, S=4096, Din=768, Dout=64.
// R11: independent barrier domains — 2 co-resident blocks/CU for both kernels.
//  R10 profile: all pipes <25% busy, 1 block/CU, whole CU idles at each
//  barrier drain. Fix: halve block, double grid.
//  attn: 4 waves (2 strips x 2 parity), QBLK=32, grid 512, LDS 56KB -> 2/CU.
//        Same triple-buffered counted-vmcnt loop (stage=4 ops -> vmcnt(4)).
//  proj: 32-row blocks, 4 waves (2 strips x 2 nh), grid 512, DOUBLE-buffer
//        minimum-2-phase (stage top, vmcnt(0)+barrier at end; WAR closed by
//        prior end-of-iter barrier), LDS 64KB -> 2/CU. x staged once (HBM
//        floor); wb re-staged per block (~147MB L2 aggregate, ~4us).

typedef __attribute__((ext_vector_type(8))) __bf16 bf16x8;
typedef __attribute__((ext_vector_type(4))) __bf16 bf16x4;
typedef __attribute__((ext_vector_type(4))) float  f32x4;

constexpr int BATCH = 4;
constexpr int SEQ   = 4096;
constexpr int DIN   = 768;
constexpr int NTOT  = 192;
constexpr int MROWS = BATCH * SEQ;  // 16384
constexpr int KVT   = 64;

__device__ __forceinline__ f32x4 mfma16(bf16x8 a, bf16x8 b, f32x4 c) {
    return __builtin_amdgcn_mfma_f32_16x16x32_bf16(a, b, c, 0, 0, 0);
}

__device__ __forceinline__ void gload_lds16(const void* g, void* l) {
    __builtin_amdgcn_global_load_lds(
        (const __attribute__((address_space(1))) void*)g,
        (__attribute__((address_space(3))) void*)l, 16, 0, 0);
}

// ---------------- k0: pack Wq|Wk|Wv -> bf16 [192][768]; Wq pre-scaled by
// 0.125*log2(e) so attention scores come out in exp2 domain.
__global__ __launch_bounds__(256) void convert_w(
        const float* __restrict__ Wq, const float* __restrict__ Wk,
        const float* __restrict__ Wv, __bf16* __restrict__ wb) {
    int i = blockIdx.x * 256 + threadIdx.x;
    if (i >= NTOT * DIN) return;
    int n = i / DIN;
    const float* src = (n < 64) ? Wq : (n < 128) ? Wk : Wv;
    float scale = (n < 64) ? 0.125f * 1.44269504f : 1.0f;
    wb[i] = (__bf16)(src[(n & 63) * DIN + (i % DIN)] * scale);
}

// ---------------- k1: q,k,v = x @ W^T  (M=16384, N=192, K=768)
// grid = 512 blocks of 32 rows; 4 waves = 2 row-strips x 2 n-halves.
// wb (24KB/ktile) + x (8KB/ktile) double-buffered via global_load_lds,
// minimum-2-phase: stage(t+1) at top, vmcnt(0)+barrier at iter end.
__global__ __launch_bounds__(256, 4) void qkv_proj(
        const float* __restrict__ x, const __bf16* __restrict__ wb,
        __bf16* __restrict__ q, __bf16* __restrict__ k, __bf16* __restrict__ vT) {
    const int tid  = threadIdx.x;
    const int wave = tid >> 6, lane = tid & 63;
    const int strip = wave & 1, nh = wave >> 1;
    const int lr = lane & 15;
    const int g  = lane >> 4;
    const int rx = (lr & 7) << 4;

    __shared__ __align__(16) char wbuf[2][NTOT * 128];   // 48 KiB
    __shared__ __align__(16) char xbuf[2][32 * 256];     // 16 KiB

    const int  srow = lane >> 3;                          // wb: 8 rows/instr
    const int  ssw  = ((lane & 7) << 4) ^ ((srow & 7) << 4);
    const int  xs4  = lane >> 4;                          // x: 4 rows/instr
    const char* wbb = (const char*)wb;
    const char* xbb = (const char*)x;
    const int  xrow0 = blockIdx.x * 32;

    auto stage = [&](int buf, int kt) {
#pragma unroll
        for (int s = 0; s < 6; ++s) {                     // wb: 6 ops/wave
            const int rbase = wave * 48 + s * 8;
            gload_lds16(wbb + (size_t)(rbase + srow) * (DIN * 2) + kt * 128 + ssw,
                        &wbuf[buf][rbase * 128]);
        }
#pragma unroll
        for (int s = 0; s < 2; ++s) {                     // x: 2 ops/wave
            const int xr = wave * 8 + s * 4;
            const int sswx = ((lane & 15) ^ ((xr & 15) + xs4)) << 4;
            gload_lds16(xbb + (size_t)(xrow0 + xr + xs4) * (DIN * 4) +
                            kt * 256 + sswx,
                        &xbuf[buf][xr * 256]);
        }
    };

    f32x4 acc[6];
#pragma unroll
    for (int t = 0; t < 6; ++t) acc[t] = f32x4{0.f, 0.f, 0.f, 0.f};

    stage(0, 0);
    asm volatile("s_waitcnt vmcnt(0) lgkmcnt(0)" ::: "memory");
    __builtin_amdgcn_s_barrier();

    constexpr int NT = DIN / 64;   // 12
    int cur = 0;
    for (int kt = 0; kt < NT; ++kt) {
        if (kt + 1 < NT) stage(cur ^ 1, kt + 1);   // readers of cur^1 passed
                                                   // the previous end barrier
#pragma unroll
        for (int ks = 0; ks < 2; ++ks) {
            const char* xrp = &xbuf[cur][(strip * 16 + lr) * 256];
            f32x4 xa = *(const f32x4*)(xrp + ((ks * 128 + g * 32)      ^ (lr << 4)));
            f32x4 xb = *(const f32x4*)(xrp + ((ks * 128 + g * 32 + 16) ^ (lr << 4)));
            bf16x8 af;
            af[0] = (__bf16)xa[0]; af[1] = (__bf16)xa[1]; af[2] = (__bf16)xa[2]; af[3] = (__bf16)xa[3];
            af[4] = (__bf16)xb[0]; af[5] = (__bf16)xb[1]; af[6] = (__bf16)xb[2]; af[7] = (__bf16)xb[3];
#pragma unroll
            for (int t = 0; t < 6; ++t) {
                const int nr = (nh * 6 + t) * 16 + lr;
                bf16x8 bf = *(const bf16x8*)(&wbuf[cur][nr * 128] +
                                             ((ks * 64 + g * 16) ^ rx));
                acc[t] = mfma16(af, bf, acc[t]);
            }
        }
        asm volatile("s_waitcnt vmcnt(0)" ::: "memory");   // prefetch landed
        __builtin_amdgcn_s_barrier();
        cur ^= 1;
    }

    const int orow = blockIdx.x * 32 + strip * 16 + g * 4;
#pragma unroll
    for (int t = 0; t < 6; ++t) {
        int n = (nh * 6 + t) * 16 + lr;
#pragma unroll
        for (int r = 0; r < 4; ++r) {
            int m = orow + r;
            __bf16 hv = (__bf16)acc[t][r];
            if (n < 64) {
                q[(size_t)m * 64 + n] = hv;
            } else if (n < 128) {
                k[(size_t)m * 64 + (n - 64)] = hv;
            } else {
                int b = m >> 12, s = m & (SEQ - 1);
                vT[(size_t)b * 64 * SEQ + (size_t)(n - 128) * SEQ + s] = hv;
            }
        }
    }
}

// ---------------- k2: flash attention, LDS-staged K/V, kv-parity waves,
// counted-vmcnt triple-buffered pipeline. 2 blocks/CU.
// grid = (SEQ/32, BATCH) = 512 blocks, 256 threads (2 q-strips x 2 kv-parity).
__global__ __launch_bounds__(256, 4) void attn(
        const __bf16* __restrict__ q, const __bf16* __restrict__ k,
        const __bf16* __restrict__ vT, float* __restrict__ out) {
    const int tid  = threadIdx.x;
    const int wave = tid >> 6, lane = tid & 63;
    const int strip = wave & 1, par = wave >> 1;
    const int b  = blockIdx.y;
    const int q0 = blockIdx.x * 32 + strip * 16;
    const int lr = lane & 15;
    const int g  = lane >> 4;
    const int lk = g * 8;
    const int rx = (lr & 7) << 4;

    const __bf16* qp = q  + (size_t)b * SEQ * 64;
    const __bf16* kp = k  + (size_t)b * SEQ * 64;
    const __bf16* vp = vT + (size_t)b * 64 * SEQ;

    __shared__ __align__(16) char kbuf[3][KVT * 128];   // 24 KiB
    __shared__ __align__(16) char vbuf[3][KVT * 128];   // 24 KiB
    __shared__ __align__(16) char pbuf[4][2048];        //  8 KiB
    char* pw = &pbuf[wave][0];

    const int  srow = lane >> 3;
    const int  ssw  = ((lane & 7) << 4) ^ ((srow & 7) << 4);

    auto stage = [&](int buf, int kv0) {   // 4 VMEM ops per wave
#pragma unroll
        for (int s = 0; s < 2; ++s) {
            const int rbase = wave * 16 + s * 8;
            gload_lds16((const char*)kp + (size_t)(kv0 + rbase + srow) * 128 + ssw,
                        &kbuf[buf][rbase * 128]);
            gload_lds16((const char*)vp + (size_t)(rbase + srow) * (SEQ * 2) +
                            (size_t)kv0 * 2 + ssw,
                        &vbuf[buf][rbase * 128]);
        }
    };

    bf16x8 qf0 = *(const bf16x8*)(qp + (size_t)(q0 + lr) * 64 + lk);
    bf16x8 qf1 = *(const bf16x8*)(qp + (size_t)(q0 + lr) * 64 + 32 + lk);

    f32x4 acc_o[4];
#pragma unroll
    for (int t = 0; t < 4; ++t) acc_o[t] = f32x4{0.f, 0.f, 0.f, 0.f};
    float l_run = 0.f;

    stage(0, 0);
    asm volatile("s_waitcnt vmcnt(0) lgkmcnt(0)" ::: "memory");
    __builtin_amdgcn_s_barrier();

    constexpr int NT = SEQ / KVT;   // 64
    int cur = 0, nxt = 1;
    for (int it = 0; it < NT; ++it) {
        stage(nxt, ((it + 1) & (NT - 1)) * KVT);          // wrap keeps count const
        asm volatile("s_waitcnt vmcnt(4) lgkmcnt(0)" ::: "memory");
        __builtin_amdgcn_s_barrier();

        // ---- S^T = K Q^T on parity's 32 kv rows (exp2 domain)
        f32x4 s4[2];
#pragma unroll
        for (int j = 0; j < 2; ++j) {
            const char* kr = &kbuf[cur][(par * 32 + j * 16 + lr) * 128];
            bf16x8 kf0 = *(const bf16x8*)(kr + ((g * 16) ^ rx));
            bf16x8 kf1 = *(const bf16x8*)(kr + ((64 + g * 16) ^ rx));
            f32x4 a = f32x4{0.f, 0.f, 0.f, 0.f};
            a = mfma16(kf0, qf0, a);
            a = mfma16(kf1, qf1, a);
            s4[j] = a;
        }

        // ---- max-free softmax; pack P (16q x 32kv, swizzled rows of 128B)
#pragma unroll
        for (int j = 0; j < 2; ++j) {
            bf16x4 pbv;
#pragma unroll
            for (int r = 0; r < 4; ++r) {
                float p = __builtin_amdgcn_exp2f(s4[j][r]);
                l_run += p;
                pbv[r] = (__bf16)p;
            }
            *(bf16x4*)(pw + lr * 128 + ((j * 32 + g * 8) ^ rx)) = pbv;
        }
        asm volatile("s_waitcnt lgkmcnt(0)" ::: "memory");

        // ---- O^T += V^T P on parity's kv slice (one 32-wide K-step)
        bf16x8 pf = *(const bf16x8*)(pw + lr * 128 + ((g * 16) ^ rx));
#pragma unroll
        for (int t = 0; t < 4; ++t) {
            const char* vr = &vbuf[cur][(t * 16 + lr) * 128];
            bf16x8 vf = *(const bf16x8*)(vr + ((par * 64 + g * 16) ^ rx));
            acc_o[t] = mfma16(vf, pf, acc_o[t]);
        }

        cur = nxt; nxt = (nxt == 2) ? 0 : nxt + 1;
    }

    // ---- parity merge (plain sums: max-free). Full fence before LDS reuse.
    l_run += __shfl_xor(l_run, 16);
    l_run += __shfl_xor(l_run, 32);
    __syncthreads();

    float* mo = (float*)(&pbuf[0][0]) + strip * 1024;   // [2][16q][64d] f32 = 8KB
    float* ml = (float*)(&kbuf[0][0]);                  // [2][16] f32 (buf0 region)
    if (par == 1) {
#pragma unroll
        for (int t = 0; t < 4; ++t)
            *(f32x4*)(mo + lr * 64 + t * 16 + g * 4) = acc_o[t];
        if (lane < 16) ml[strip * 16 + lr] = l_run;
    }
    __syncthreads();
    if (par == 0) {
        float inv = 1.f / (l_run + ml[strip * 16 + lr]);
        float* ob = out + ((size_t)b * SEQ + q0 + lr) * 64;
#pragma unroll
        for (int t = 0; t < 4; ++t) {
            f32x4 o1 = *(const f32x4*)(mo + lr * 64 + t * 16 + g * 4);
            f32x4 o4;
#pragma unroll
            for (int r = 0; r < 4; ++r) o4[r] = (acc_o[t][r] + o1[r]) * inv;
            *(f32x4*)(ob + t * 16 + g * 4) = o4;
        }
    }
}

extern "C" void kernel_launch(void* const* d_in, const int* in_sizes, int n_in,
                              void* d_out, int out_size, void* d_ws, size_t ws_size,
                              hipStream_t stream) {
    const float* x  = (const float*)d_in[0];
    const float* Wq = (const float*)d_in[1];
    const float* Wk = (const float*)d_in[2];
    const float* Wv = (const float*)d_in[3];
    float* out = (float*)d_out;

    char* ws = (char*)d_ws;
    __bf16* wb = (__bf16*)(ws);
    __bf16* qb = (__bf16*)(ws + 294912);
    __bf16* kb = (__bf16*)(ws + 294912 + 2097152);
    __bf16* vT = (__bf16*)(ws + 294912 + 2u * 2097152);

    convert_w<<<dim3((NTOT * DIN + 255) / 256), dim3(256), 0, stream>>>(Wq, Wk, Wv, wb);
    qkv_proj<<<dim3(MROWS / 32), dim3(256), 0, stream>>>(x, wb, qb, kb, vT);
    attn<<<dim3(SEQ / 32, BATCH), dim3(256), 0, stream>>>(qb, kb, vT, out);
}

// Round 12
// 53.775 us; speedup vs baseline: 1.3448x; 1.3448x over previous
//
#include <hip/hip_runtime.h>
#include <hip/hip_bf16.h>

// SelfAttention: B=4, S=4096, Din=768, Dout=64.
// R12: waves/SIMD at fixed staging (R11 lesson: smaller blocks doubled staging
//  traffic and didn't raise waves/CU).
//  attn: QBLK=64, 16 waves (4 q-strips x 4 kv-parities), 1024 thr, grid 256
//        = 1 block/CU, 16 waves/CU = 4/SIMD (was 2). KVT=128: per-parity body
//        is byte-identical to the validated 32-kv-row R10 body; NT 64->32;
//        staging total unchanged (K/V staged once per 64 q-rows).
//        Stage = 2 ops/wave -> vmcnt(2). LDS 48+48+32 = 128KB.
//  proj: exact R10 version (triple-buffer, vmcnt(5)) — R11 variant only
//        added wb re-staging.

typedef __attribute__((ext_vector_type(8))) __bf16 bf16x8;
typedef __attribute__((ext_vector_type(4))) __bf16 bf16x4;
typedef __attribute__((ext_vector_type(4))) float  f32x4;

constexpr int BATCH = 4;
constexpr int SEQ   = 4096;
constexpr int DIN   = 768;
constexpr int NTOT  = 192;
constexpr int MROWS = BATCH * SEQ;  // 16384
constexpr int KVT   = 128;          // kv tile (128 rows x 128B K, 64 x 256B V)

__device__ __forceinline__ f32x4 mfma16(bf16x8 a, bf16x8 b, f32x4 c) {
    return __builtin_amdgcn_mfma_f32_16x16x32_bf16(a, b, c, 0, 0, 0);
}

__device__ __forceinline__ void gload_lds16(const void* g, void* l) {
    __builtin_amdgcn_global_load_lds(
        (const __attribute__((address_space(1))) void*)g,
        (__attribute__((address_space(3))) void*)l, 16, 0, 0);
}

// ---------------- k0: pack Wq|Wk|Wv -> bf16 [192][768]; Wq pre-scaled by
// 0.125*log2(e) so attention scores come out in exp2 domain.
__global__ __launch_bounds__(256) void convert_w(
        const float* __restrict__ Wq, const float* __restrict__ Wk,
        const float* __restrict__ Wv, __bf16* __restrict__ wb) {
    int i = blockIdx.x * 256 + threadIdx.x;
    if (i >= NTOT * DIN) return;
    int n = i / DIN;
    const float* src = (n < 64) ? Wq : (n < 128) ? Wk : Wv;
    float scale = (n < 64) ? 0.125f * 1.44269504f : 1.0f;
    wb[i] = (__bf16)(src[(n & 63) * DIN + (i % DIN)] * scale);
}

// ---------------- k1: q,k,v = x @ W^T  (M=16384, N=192, K=768)  [= R10]
// grid = 256 blocks of 64 rows; 8 waves = 4 row-strips x 2 n-halves.
// wb (24KB/ktile) AND x (16KB/ktile) staged via global_load_lds,
// triple-buffered, counted vmcnt(5) per iter.
__global__ __launch_bounds__(512, 2) void qkv_proj(
        const float* __restrict__ x, const __bf16* __restrict__ wb,
        __bf16* __restrict__ q, __bf16* __restrict__ k, __bf16* __restrict__ vT) {
    const int tid  = threadIdx.x;
    const int wave = tid >> 6, lane = tid & 63;
    const int strip = wave & 3, nh = wave >> 2;
    const int lr = lane & 15;
    const int g  = lane >> 4;
    const int rx = (lr & 7) << 4;

    __shared__ __align__(16) char wbuf[3][NTOT * 128];   // 72 KiB
    __shared__ __align__(16) char xbuf[3][64 * 256];     // 48 KiB

    const int  srow = lane >> 3;                          // wb: 8 rows/instr
    const int  ssw  = ((lane & 7) << 4) ^ ((srow & 7) << 4);
    const int  xs4  = lane >> 4;                          // x: 4 rows/instr
    const char* wbb = (const char*)wb;
    const char* xbb = (const char*)x;
    const int  xrow0 = blockIdx.x * 64;

    auto stage = [&](int buf, int kt) {
#pragma unroll
        for (int s = 0; s < 3; ++s) {                     // wb: 3 ops
            const int rbase = wave * 24 + s * 8;
            gload_lds16(wbb + (size_t)(rbase + srow) * (DIN * 2) + kt * 128 + ssw,
                        &wbuf[buf][rbase * 128]);
        }
#pragma unroll
        for (int s = 0; s < 2; ++s) {                     // x: 2 ops
            const int xr = wave * 8 + s * 4;
            const int sswx = ((lane & 15) ^ ((xr & 15) + xs4)) << 4;
            gload_lds16(xbb + (size_t)(xrow0 + xr + xs4) * (DIN * 4) +
                            kt * 256 + sswx,
                        &xbuf[buf][xr * 256]);
        }
    };

    f32x4 acc[6];
#pragma unroll
    for (int t = 0; t < 6; ++t) acc[t] = f32x4{0.f, 0.f, 0.f, 0.f};

    stage(0, 0);
    asm volatile("s_waitcnt vmcnt(0) lgkmcnt(0)" ::: "memory");
    __builtin_amdgcn_s_barrier();

    constexpr int NT = DIN / 64;   // 12
    int cur = 0, nxt = 1;
    for (int kt = 0; kt < NT; ++kt) {
        stage(nxt, (kt + 1 == NT) ? 0 : kt + 1);          // wrap keeps count const
        asm volatile("s_waitcnt vmcnt(5) lgkmcnt(0)" ::: "memory");
        __builtin_amdgcn_s_barrier();

#pragma unroll
        for (int ks = 0; ks < 2; ++ks) {
            const char* xrp = &xbuf[cur][(strip * 16 + lr) * 256];
            f32x4 xa = *(const f32x4*)(xrp + ((ks * 128 + g * 32)      ^ (lr << 4)));
            f32x4 xb = *(const f32x4*)(xrp + ((ks * 128 + g * 32 + 16) ^ (lr << 4)));
            bf16x8 af;
            af[0] = (__bf16)xa[0]; af[1] = (__bf16)xa[1]; af[2] = (__bf16)xa[2]; af[3] = (__bf16)xa[3];
            af[4] = (__bf16)xb[0]; af[5] = (__bf16)xb[1]; af[6] = (__bf16)xb[2]; af[7] = (__bf16)xb[3];
#pragma unroll
            for (int t = 0; t < 6; ++t) {
                const int nr = (nh * 6 + t) * 16 + lr;
                bf16x8 bf = *(const bf16x8*)(&wbuf[cur][nr * 128] +
                                             ((ks * 64 + g * 16) ^ rx));
                acc[t] = mfma16(af, bf, acc[t]);
            }
        }
        cur = nxt; nxt = (nxt == 2) ? 0 : nxt + 1;
    }

    const int orow = blockIdx.x * 64 + strip * 16 + g * 4;
#pragma unroll
    for (int t = 0; t < 6; ++t) {
        int n = (nh * 6 + t) * 16 + lr;
#pragma unroll
        for (int r = 0; r < 4; ++r) {
            int m = orow + r;
            __bf16 hv = (__bf16)acc[t][r];
            if (n < 64) {
                q[(size_t)m * 64 + n] = hv;
            } else if (n < 128) {
                k[(size_t)m * 64 + (n - 64)] = hv;
            } else {
                int b = m >> 12, s = m & (SEQ - 1);
                vT[(size_t)b * 64 * SEQ + (size_t)(n - 128) * SEQ + s] = hv;
            }
        }
    }
}

// ---------------- k2: flash attention, LDS-staged K/V, 16 waves.
// grid = (SEQ/64, BATCH) = 256 blocks, 1024 threads
// (4 q-strips x 4 kv-parities). Parity p computes kv rows [p*32, p*32+32)
// of each staged 128-row tile. Triple-buffered, counted vmcnt(2).
__global__ __launch_bounds__(1024, 4) void attn(
        const __bf16* __restrict__ q, const __bf16* __restrict__ k,
        const __bf16* __restrict__ vT, float* __restrict__ out) {
    const int tid  = threadIdx.x;
    const int wave = tid >> 6, lane = tid & 63;
    const int strip = wave & 3, par = wave >> 2;
    const int b  = blockIdx.y;
    const int q0 = blockIdx.x * 64 + strip * 16;
    const int lr = lane & 15;
    const int g  = lane >> 4;
    const int lk = g * 8;
    const int rx = (lr & 7) << 4;

    const __bf16* qp = q  + (size_t)b * SEQ * 64;
    const __bf16* kp = k  + (size_t)b * SEQ * 64;
    const __bf16* vp = vT + (size_t)b * 64 * SEQ;

    __shared__ __align__(16) char kbuf[3][KVT * 128];   // 48 KiB (128r x 128B)
    __shared__ __align__(16) char vbuf[3][64 * 256];    // 48 KiB (64r x 256B)
    __shared__ __align__(16) char pbuf[16][2048];       // 32 KiB
    char* pw = &pbuf[wave][0];

    const int  srow8 = lane >> 3;                        // K: 8 rows/instr
    const int  sswK  = ((lane & 7) << 4) ^ ((srow8 & 7) << 4);
    const int  vrow  = wave * 4 + (lane >> 4);           // V: 4 rows/instr
    const int  sswV  = ((lane & 15) ^ (vrow & 7)) << 4;

    auto stage = [&](int buf, int kv0) {   // exactly 2 VMEM ops per wave
        gload_lds16((const char*)kp + (size_t)(kv0 + wave * 8 + srow8) * 128 + sswK,
                    &kbuf[buf][wave * 8 * 128]);
        gload_lds16((const char*)vp + (size_t)vrow * (SEQ * 2) +
                        (size_t)kv0 * 2 + sswV,
                    &vbuf[buf][wave * 4 * 256]);
    };

    bf16x8 qf0 = *(const bf16x8*)(qp + (size_t)(q0 + lr) * 64 + lk);
    bf16x8 qf1 = *(const bf16x8*)(qp + (size_t)(q0 + lr) * 64 + 32 + lk);

    f32x4 acc_o[4];
#pragma unroll
    for (int t = 0; t < 4; ++t) acc_o[t] = f32x4{0.f, 0.f, 0.f, 0.f};
    float l_run = 0.f;

    stage(0, 0);
    asm volatile("s_waitcnt vmcnt(0) lgkmcnt(0)" ::: "memory");
    __builtin_amdgcn_s_barrier();

    constexpr int NT = SEQ / KVT;   // 32
    int cur = 0, nxt = 1;
    for (int it = 0; it < NT; ++it) {
        stage(nxt, ((it + 1) & (NT - 1)) * KVT);          // wrap keeps count const
        asm volatile("s_waitcnt vmcnt(2) lgkmcnt(0)" ::: "memory");
        __builtin_amdgcn_s_barrier();

        // ---- S^T = K Q^T on parity's 32 kv rows (exp2 domain)
        f32x4 s4[2];
#pragma unroll
        for (int j = 0; j < 2; ++j) {
            const char* kr = &kbuf[cur][(par * 32 + j * 16 + lr) * 128];
            bf16x8 kf0 = *(const bf16x8*)(kr + ((g * 16) ^ rx));
            bf16x8 kf1 = *(const bf16x8*)(kr + ((64 + g * 16) ^ rx));
            f32x4 a = f32x4{0.f, 0.f, 0.f, 0.f};
            a = mfma16(kf0, qf0, a);
            a = mfma16(kf1, qf1, a);
            s4[j] = a;
        }

        // ---- max-free softmax; pack P (16q x 32kv, swizzled rows of 128B)
#pragma unroll
        for (int j = 0; j < 2; ++j) {
            bf16x4 pbv;
#pragma unroll
            for (int r = 0; r < 4; ++r) {
                float p = __builtin_amdgcn_exp2f(s4[j][r]);
                l_run += p;
                pbv[r] = (__bf16)p;
            }
            *(bf16x4*)(pw + lr * 128 + ((j * 32 + g * 8) ^ rx)) = pbv;
        }
        asm volatile("s_waitcnt lgkmcnt(0)" ::: "memory");

        // ---- O^T += V^T P on parity's kv slice (one 32-wide K-step)
        bf16x8 pf = *(const bf16x8*)(pw + lr * 128 + ((g * 16) ^ rx));
#pragma unroll
        for (int t = 0; t < 4; ++t) {
            const char* vr = &vbuf[cur][(t * 16 + lr) * 256];
            bf16x8 vf = *(const bf16x8*)(vr + ((par * 64 + g * 16) ^ rx));
            acc_o[t] = mfma16(vf, pf, acc_o[t]);
        }

        cur = nxt; nxt = (nxt == 2) ? 0 : nxt + 1;
    }

    // ---- 4-parity merge (plain sums: max-free). kbuf/vbuf dead -> reuse.
    l_run += __shfl_xor(l_run, 16);
    l_run += __shfl_xor(l_run, 32);
    __syncthreads();   // full drain (incl. wrap prefetch) before LDS reuse

    float* mo = (float*)(&kbuf[0][0]);   // [3][4][16][64] f32 = 48 KiB
    float* ml = (float*)(&vbuf[0][0]);   // [3][4][16] f32
    if (par > 0) {
        const int pi = par - 1;
        float* dst = mo + (size_t)((pi * 4 + strip) * 16 + lr) * 64;
#pragma unroll
        for (int t = 0; t < 4; ++t)
            *(f32x4*)(dst + t * 16 + g * 4) = acc_o[t];
        if (lane < 16) ml[(pi * 4 + strip) * 16 + lr] = l_run;
    }
    __syncthreads();
    if (par == 0) {
        float L = l_run;
#pragma unroll
        for (int pi = 0; pi < 3; ++pi) L += ml[(pi * 4 + strip) * 16 + lr];
        float inv = 1.f / L;
        float* ob = out + ((size_t)b * SEQ + q0 + lr) * 64;
#pragma unroll
        for (int t = 0; t < 4; ++t) {
            f32x4 o4 = acc_o[t];
#pragma unroll
            for (int pi = 0; pi < 3; ++pi)
                o4 += *(const f32x4*)(mo + (size_t)((pi * 4 + strip) * 16 + lr) * 64 +
                                      t * 16 + g * 4);
#pragma unroll
            for (int r = 0; r < 4; ++r) o4[r] *= inv;
            *(f32x4*)(ob + t * 16 + g * 4) = o4;
        }
    }
}

extern "C" void kernel_launch(void* const* d_in, const int* in_sizes, int n_in,
                              void* d_out, int out_size, void* d_ws, size_t ws_size,
                              hipStream_t stream) {
    const float* x  = (const float*)d_in[0];
    const float* Wq = (const float*)d_in[1];
    const float* Wk = (const float*)d_in[2];
    const float* Wv = (const float*)d_in[3];
    float* out = (float*)d_out;

    char* ws = (char*)d_ws;
    __bf16* wb = (__bf16*)(ws);
    __bf16* qb = (__bf16*)(ws + 294912);
    __bf16* kb = (__bf16*)(ws + 294912 + 2097152);
    __bf16* vT = (__bf16*)(ws + 294912 + 2u * 2097152);

    convert_w<<<dim3((NTOT * DIN + 255) / 256), dim3(256), 0, stream>>>(Wq, Wk, Wv, wb);
    qkv_proj<<<dim3(MROWS / 64), dim3(512), 0, stream>>>(x, wb, qb, kb, vT);
    attn<<<dim3(SEQ / 64, BATCH), dim3(1024), 0, stream>>>(qb, kb, vT, out);
}